// Round 2
// baseline (551.908 us; speedup 1.0000x reference)
//
#include <hip/hip_runtime.h>
#include <cfloat>
#include <math.h>

#define KCB 512   // codebook entries
#define DD  64    // dim
#define BN  64    // rows per block
#define KC  128   // codebook chunk per LDS stage

// numpy pairwise_sum (n=64, fits the <=128 branch) over fl(p_i^2):
// r[j] = a[j]; for i=8..56 step 8: r[j] += a[i+j]; tree-combine.
// Plain mul + add, NO fma contraction (matches np.sum(x*x, axis=1)).
__device__ __forceinline__ float np_sumsq64(const float* p, int stride) {
#pragma clang fp contract(off)
    float r[8];
    #pragma unroll
    for (int j = 0; j < 8; ++j) { const float v = p[j * stride]; r[j] = v * v; }
    #pragma unroll
    for (int i = 8; i < 64; i += 8) {
        #pragma unroll
        for (int j = 0; j < 8; ++j) { const float v = p[(i + j) * stride]; r[j] = r[j] + v * v; }
    }
    return ((r[0] + r[1]) + (r[2] + r[3])) + ((r[4] + r[5]) + (r[6] + r[7]));
}

__global__ void csqr_kernel(const float* __restrict__ cb, float* __restrict__ csq) {
    int k = blockIdx.x * blockDim.x + threadIdx.x;
    if (k < KCB) csq[k] = np_sumsq64(cb + (size_t)k * DD, 1);
}

__global__ __launch_bounds__(256) void vq_kernel(const float* __restrict__ z,
                                                 const float* __restrict__ cb,
                                                 const float* __restrict__ csq_g,
                                                 float* __restrict__ out0,
                                                 float* __restrict__ out1,
                                                 float* __restrict__ outI) {
    __shared__ float xs[DD][BN];       // x tile, d-major (transposed)
    __shared__ float cs[DD][KC + 4];   // codebook chunk, d-major
    __shared__ float csq_s[KC];
    __shared__ float As[BN];           // numpy-exact ||x||^2 per row
    __shared__ int   ridx[BN];

    const int tid = threadIdx.x;
    const int tr  = tid >> 4;   // 0..15 -> rows tr*4..tr*4+3
    const int tc  = tid & 15;   // 0..15 -> cols tc*8..tc*8+7 (within chunk)
    const int r0  = blockIdx.x * BN;

    // ---- stage x tile (transposed)
    {
        const int row = tid & 63;
        const int d4b = (tid >> 6) * 4;
        #pragma unroll
        for (int it = 0; it < 4; ++it) {
            const int d4 = d4b + it * 16;
            const float4 v = *(const float4*)(z + (size_t)(r0 + row) * DD + d4);
            xs[d4 + 0][row] = v.x;
            xs[d4 + 1][row] = v.y;
            xs[d4 + 2][row] = v.z;
            xs[d4 + 3][row] = v.w;
        }
    }
    __syncthreads();
    // ---- numpy-exact x_sqr per row (wave 0; 2-way LDS aliasing = free)
    if (tid < BN) As[tid] = np_sumsq64(&xs[0][tid], BN);

    float m1[4];
    int   i1[4];
    #pragma unroll
    for (int r = 0; r < 4; ++r) { m1[r] = FLT_MAX; i1[r] = KCB; }

    for (int ch = 0; ch < KCB / KC; ++ch) {
        const int kc0 = ch * KC;
        __syncthreads();   // protects cs reuse; (ch==0) covers As
        // ---- stage codebook chunk (transposed)
        {
            const int k   = tid & 127;
            const int d4b = (tid >> 7) * 4;
            #pragma unroll
            for (int it = 0; it < 8; ++it) {
                const int d4 = d4b + it * 8;
                const float4 v = *(const float4*)(cb + (size_t)(kc0 + k) * DD + d4);
                cs[d4 + 0][k] = v.x;
                cs[d4 + 1][k] = v.y;
                cs[d4 + 2][k] = v.z;
                cs[d4 + 3][k] = v.w;
            }
            if (tid < KC) csq_s[tid] = csq_g[kc0 + tid];
        }
        __syncthreads();

        // ---- dot products: single ascending-d fmaf chain per (row,code),
        // bitwise-matching OpenBLAS sgemm k-accumulation.
        float acc[4][8];
        #pragma unroll
        for (int r = 0; r < 4; ++r)
            #pragma unroll
            for (int j = 0; j < 8; ++j) acc[r][j] = 0.f;

        #pragma unroll 4
        for (int d = 0; d < DD; ++d) {
            const float4 xf = *(const float4*)&xs[d][tr * 4];
            const float4 c0 = *(const float4*)&cs[d][tc * 8];
            const float4 c1 = *(const float4*)&cs[d][tc * 8 + 4];
            const float xr[4] = {xf.x, xf.y, xf.z, xf.w};
            const float cc[8] = {c0.x, c0.y, c0.z, c0.w, c1.x, c1.y, c1.z, c1.w};
            #pragma unroll
            for (int r = 0; r < 4; ++r)
                #pragma unroll
                for (int j = 0; j < 8; ++j)
                    acc[r][j] = fmaf(xr[r], cc[j], acc[r][j]);
        }

        // ---- numpy formula rounding: D = fl(fl(A + c2) - fl(2*dot));
        // 2*dot is exact, so the fused form is bit-identical. Strict < keeps
        // the lowest k (k ascending within each lane).
        {
#pragma clang fp contract(off)
            float a4[4];
            #pragma unroll
            for (int r = 0; r < 4; ++r) a4[r] = As[tr * 4 + r];
            #pragma unroll
            for (int j = 0; j < 8; ++j) {
                const int   kg = kc0 + tc * 8 + j;
                const float cq = csq_s[tc * 8 + j];
                #pragma unroll
                for (int r = 0; r < 4; ++r) {
                    const float s = (a4[r] + cq) - 2.0f * acc[r][j];
                    if (s < m1[r]) { m1[r] = s; i1[r] = kg; }
                }
            }
        }
    }

    // ---- reduce (min, idx) across the 16 tc lanes; lowest-index tie-break
    #pragma unroll
    for (int m = 1; m < 16; m <<= 1) {
        #pragma unroll
        for (int r = 0; r < 4; ++r) {
            const float om = __shfl_xor(m1[r], m);
            const int   oi = __shfl_xor(i1[r], m);
            if (om < m1[r] || (om == m1[r] && oi < i1[r])) { m1[r] = om; i1[r] = oi; }
        }
    }
    if (tc == 0) {
        #pragma unroll
        for (int r = 0; r < 4; ++r) ridx[tr * 4 + r] = i1[r];
    }
    __syncthreads();

    // ---- epilogue: q = cb[idx]; out0 = fl(z + fl(q - z)); out1 = q; indices
    {
        #pragma unroll
        for (int it = 0; it < 4; ++it) {
            const int i   = it * 256 + tid;
            const int row = i >> 4;
            const int d4  = (i & 15) * 4;
            const int idx = ridx[row];
            const float4 q = *(const float4*)(cb + (size_t)idx * DD + d4);
            float4 zv;
            zv.x = xs[d4 + 0][row];
            zv.y = xs[d4 + 1][row];
            zv.z = xs[d4 + 2][row];
            zv.w = xs[d4 + 3][row];
            float4 o0;
            {
#pragma clang fp contract(off)
                o0.x = zv.x + (q.x - zv.x);
                o0.y = zv.y + (q.y - zv.y);
                o0.z = zv.z + (q.z - zv.z);
                o0.w = zv.w + (q.w - zv.w);
            }
            *(float4*)(out0 + (size_t)(r0 + row) * DD + d4) = o0;
            *(float4*)(out1 + (size_t)(r0 + row) * DD + d4) = q;
        }
        if (tid < BN) outI[r0 + tid] = (float)ridx[tid];
    }
}

extern "C" void kernel_launch(void* const* d_in, const int* in_sizes, int n_in,
                              void* d_out, int out_size, void* d_ws, size_t ws_size,
                              hipStream_t stream) {
    const float* z  = (const float*)d_in[0];
    const float* cb = (const float*)d_in[1];
    float* out = (float*)d_out;
    const int ND = in_sizes[0];          // N*D
    const int N  = ND / DD;              // 524288
    float* csq  = (float*)d_ws;          // K floats scratch
    float* out0 = out;                                   // z_q_x
    float* out1 = out + (size_t)N * DD;                  // z_q_x_bar
    float* outI = out + 2 * (size_t)N * DD;              // indices (as float)

    csqr_kernel<<<(KCB + 255) / 256, 256, 0, stream>>>(cb, csq);
    vq_kernel<<<N / BN, 256, 0, stream>>>(z, cb, csq, out0, out1, outI);
}